// Round 6
// baseline (381.990 us; speedup 1.0000x reference)
//
#include <hip/hip_runtime.h>
#include <stdint.h>

#define GRID_Z 10
#define GRID_Y 400
#define GRID_X 352
#define NGRID (GRID_Z * GRID_Y * GRID_X)   // 1,408,000
#define NVOX 200000
#define CCH 128
#define MROI 64
#define GXD 64
#define GYD 32
#define GZD 4
#define GCELLS 8192                         // GXD*GYD*GZD
#define NTAPS 147                           // 7*7*3
#define FPAD 132                            // feat LDS row pitch (128+4)
#define TROWS 32                            // voxel rows per tile

// Recompute a grid cell's world xyz exactly like the reference (fp32, no fma
// contraction so floor() boundaries match XLA's mul+add evaluation).
__device__ __forceinline__ void cell_xyz(const float* __restrict__ roi, int g,
                                         float& X, float& Y, float& Z) {
#pragma clang fp contract(off)
    int iz = g & 3;
    int iy = (g >> 2) & 31;
    int ix = g >> 7;
    float bx = roi[3] * 2.0f;   // EXTEND on x,y dims
    float by = roi[4] * 2.0f;
    float bz = roi[5];
    float lx = (ix + 0.5f) / 64.0f * bx - bx / 2.0f;
    float ly = (iy + 0.5f) / 32.0f * by - by / 2.0f;
    float lz = (iz + 0.5f) / 4.0f  * bz - bz / 2.0f;
    float c = cosf(roi[6]);
    float s = sinf(roi[6]);
    X = lx * c + ly * (-s) + roi[0];
    Y = lx * s + ly * c    + roi[1];
    Z = lz + roi[2];
}

__global__ void k_scatter(const int* __restrict__ vcoords, int* __restrict__ v2p) {
    int i = blockIdx.x * 256 + threadIdx.x;
    if (i >= NVOX) return;
    int z = vcoords[i * 4 + 1];
    int y = vcoords[i * 4 + 2];
    int x = vcoords[i * 4 + 3];
    // Duplicate coords: XLA scatter applies updates in order -> last (max idx) wins.
    atomicMax(&v2p[(z * GRID_Y + y) * GRID_X + x], i);
}

// Per (m, g): map grid cell to voxel index; ballot-compact valid (p,g) pairs
// into a per-ROI list (order nondeterministic; only perturbs fp sum order).
__global__ void k_build(const float* __restrict__ rois, const int* __restrict__ v2p,
                        unsigned* __restrict__ list, int* __restrict__ cnt) {
#pragma clang fp contract(off)
    int g = blockIdx.x * 256 + threadIdx.x;   // [0, GCELLS)
    int m = blockIdx.y;
    int lane = threadIdx.x & 63;
    const float* roi = rois + m * 7;
    float X, Y, Z;
    cell_xyz(roi, g, X, Y, Z);
    float fx = floorf((X - 0.0f)     / 0.05f);
    float fy = floorf((Y - (-40.0f)) / 0.05f);
    float fz = floorf((Z - (-3.0f))  / 0.1f);
    int cx = (int)floorf(fx / 4.0f);
    int cy = (int)floorf(fy / 4.0f);
    int cz = (int)floorf(fz / 4.0f);
    int p = -1;
    if (cz >= 0 && cz < GRID_Z && cy >= 0 && cy < GRID_Y && cx >= 0 && cx < GRID_X)
        p = v2p[(cz * GRID_Y + cy) * GRID_X + cx];
    bool v = p >= 0;
    unsigned long long bal = __ballot(v);
    int nset = __popcll(bal);
    int base = 0;
    if (lane == 0 && nset) base = atomicAdd(&cnt[m], nset);
    base = __shfl(base, 0, 64);
    if (v) {
        int pos = __popcll(bal & ((1ull << lane) - 1ull));
        list[m * GCELLS + base + pos] = ((unsigned)p << 13) | (unsigned)g;
    }
}

// Batched-GEMM dots + LDS scatter. Block (s, m): private 32 KB LDS score for
// ROI m; tiles of 32 voxels staged in LDS; wave w owns taps [40w,40w+40);
// lane (vi=l&7, ti=(l>>3)&7) computes a 4-voxel x 5-tap register tile over
// K=128. Dots deposit via ds_add_f32 (LDS atomic - no TCC traffic). Epilogue
// writes the 32 KB partial to global with plain coalesced stores.
__global__ __launch_bounds__(256) void k_dots(
        const float* __restrict__ vfeat, const float* __restrict__ fproto,
        const unsigned* __restrict__ list, const int* __restrict__ cnt,
        float* __restrict__ partial) {
    __shared__ float    sscore[GCELLS];        // 32 KB
    __shared__ float    sfeat[TROWS * FPAD];   // 16.9 KB
    __shared__ unsigned sg[TROWS];

    const int m    = blockIdx.y;
    const int NS   = gridDim.x;
    const int tid  = threadIdx.x;
    const int w    = tid >> 6;                 // wave 0..3
    const int lane = tid & 63;
    const int vi   = lane & 7;
    const int ti   = (lane >> 3) & 7;
    const int n    = cnt[m];
    const unsigned* lst = list + m * GCELLS;
    const int tbase = w * 40 + ti;             // thread's taps: tbase + 8b, b=0..4

    {   // zero the private score tile
        float4* s4 = (float4*)sscore;
        #pragma unroll
        for (int i = 0; i < GCELLS / 4 / 256; ++i)
            s4[tid + 256 * i] = make_float4(0.f, 0.f, 0.f, 0.f);
    }

    for (int vt0 = blockIdx.x * TROWS; vt0 < n; vt0 += TROWS * NS) {
        __syncthreads();                       // score-zero / prior epilogue done
        {   // stage 32 feat rows: 8 threads per row, 16 floats each
            int r = tid >> 3;                  // row 0..31
            int q = tid & 7;                   // 16-float chunk
            int v = vt0 + r;
            unsigned e = 0xFFFFFFFFu;
            if (v < n) e = lst[v];
            if (q == 0) sg[r] = e;
            if (e != 0xFFFFFFFFu) {
                int p = (int)(e >> 13);
                const float4* src = (const float4*)(vfeat + (size_t)p * CCH) + q * 4;
                float4* drow = (float4*)(sfeat + r * FPAD + q * 16);
                #pragma unroll
                for (int j = 0; j < 4; ++j) drow[j] = src[j];
            }
        }
        __syncthreads();

        float acc[4][5];
        #pragma unroll
        for (int a = 0; a < 4; ++a)
            #pragma unroll
            for (int b = 0; b < 5; ++b) acc[a][b] = 0.0f;

        #pragma unroll 1
        for (int k = 0; k < CCH; k += 4) {
            float4 f[4];
            #pragma unroll
            for (int a = 0; a < 4; ++a)
                f[a] = *(const float4*)&sfeat[(vi + 8 * a) * FPAD + k];
            float4 wv[5];
            #pragma unroll
            for (int b = 0; b < 5; ++b) {
                int t = tbase + 8 * b;
                int tc = t > (NTAPS - 1) ? (NTAPS - 1) : t;   // clamp: no OOB read
                wv[b] = *(const float4*)(fproto + tc * CCH + k);
            }
            #pragma unroll
            for (int a = 0; a < 4; ++a)
                #pragma unroll
                for (int b = 0; b < 5; ++b) {
                    acc[a][b] = fmaf(f[a].x, wv[b].x, acc[a][b]);
                    acc[a][b] = fmaf(f[a].y, wv[b].y, acc[a][b]);
                    acc[a][b] = fmaf(f[a].z, wv[b].z, acc[a][b]);
                    acc[a][b] = fmaf(f[a].w, wv[b].w, acc[a][b]);
                }
        }

        // deposit dots into the private LDS score grid (ds_add_f32 atomics)
        #pragma unroll
        for (int b = 0; b < 5; ++b) {
            int t = tbase + 8 * b;
            if (t >= NTAPS) continue;
            int kx  = t / 21;
            int rem = t - kx * 21;
            int ky  = rem / 3;
            int kz  = rem - ky * 3;
            #pragma unroll
            for (int a = 0; a < 4; ++a) {
                unsigned e = sg[vi + 8 * a];
                if (e == 0xFFFFFFFFu) continue;
                int g  = (int)(e & 8191u);
                int cx = (g >> 7)        - (kx - 3);
                int cy = ((g >> 2) & 31) - (ky - 3);
                int cz = (g & 3)         - (kz - 1);
                if ((unsigned)cx < (unsigned)GXD && (unsigned)cy < (unsigned)GYD &&
                    (unsigned)cz < (unsigned)GZD)
                    atomicAdd(&sscore[(cx << 7) | (cy << 2) | cz], acc[a][b]);
            }
        }
    }

    __syncthreads();                           // all waves' deposits done
    {   // coalesced partial writeback (covers every cell -> no global zeroing)
        float* dst = partial + ((size_t)m * NS + blockIdx.x) * GCELLS;
        const float4* s4 = (const float4*)sscore;
        float4* d4 = (float4*)dst;
        #pragma unroll
        for (int i = 0; i < GCELLS / 4 / 256; ++i)
            d4[tid + 256 * i] = s4[tid + 256 * i];
    }
}

// Fused partial-merge + argmax + output write: one block per ROI.
__global__ void k_argfin(const float* __restrict__ partial, int ns,
                         const float* __restrict__ rois,
                         const float* __restrict__ pbox,
                         float* __restrict__ out) {
    __shared__ unsigned long long red[256];
    int m = blockIdx.x;
    int tid = threadIdx.x;
    const float* base = partial + (size_t)m * ns * GCELLS;
    unsigned long long bk = 0ull;
    for (int g = tid; g < GCELLS; g += 256) {
        float v = 0.0f;
        for (int s = 0; s < ns; ++s) v += base[s * GCELLS + g];
        unsigned ub  = __float_as_uint(v);
        unsigned key = (ub & 0x80000000u) ? ~ub : (ub | 0x80000000u);  // order-preserving
        unsigned long long pk =
            ((unsigned long long)key << 32) | (unsigned)(GCELLS - 1 - g);  // ties -> smallest g
        bk = bk > pk ? bk : pk;
    }
    red[tid] = bk;
    __syncthreads();
    for (int s = 128; s > 0; s >>= 1) {
        if (tid < s) {
            unsigned long long o = red[tid + s];
            if (o > red[tid]) red[tid] = o;
        }
        __syncthreads();
    }
    if (tid == 0) {
        int g = (GCELLS - 1) - (int)(unsigned)(red[0] & 0xFFFFFFFFu);
        float X, Y, Z;
        cell_xyz(rois + m * 7, g, X, Y, Z);
        out[m * 7 + 0] = X;
        out[m * 7 + 1] = Y;
        out[m * 7 + 2] = Z;
        out[m * 7 + 3] = pbox[3];
        out[m * 7 + 4] = pbox[4];
        out[m * 7 + 5] = pbox[5];
        out[m * 7 + 6] = pbox[6];
    }
}

extern "C" void kernel_launch(void* const* d_in, const int* in_sizes, int n_in,
                              void* d_out, int out_size, void* d_ws, size_t ws_size,
                              hipStream_t stream) {
    const float* rois    = (const float*)d_in[0];
    const float* pbox    = (const float*)d_in[1];
    const float* vfeat   = (const float*)d_in[2];
    const float* fproto  = (const float*)d_in[3];
    const int*   vcoords = (const int*)d_in[4];
    float* out = (float*)d_out;

    // ws layout: v2p | list | cnt(256B) | partial (separate if room, else
    // aliases v2p with NS=2 -- 2*64*8192 floats = 1.05M <= NGRID, and v2p is
    // dead after k_build).
    int*      v2p  = (int*)d_ws;                               // NGRID ints (5.63 MB)
    unsigned* list = (unsigned*)(v2p + NGRID);                 // MROI*GCELLS (2.10 MB)
    int*      cnt  = (int*)(list + MROI * GCELLS);             // 64 ints (256 B slot)
    size_t    base = ((size_t)NGRID + (size_t)MROI * GCELLS) * 4 + 256;
    int NS; float* partial;
    if (ws_size >= base + (size_t)8 * MROI * GCELLS * 4) {
        NS = 8;  partial = (float*)((char*)d_ws + base);       // 16 MB region
    } else if (ws_size >= base + (size_t)4 * MROI * GCELLS * 4) {
        NS = 4;  partial = (float*)((char*)d_ws + base);       // 8 MB region
    } else {
        NS = 2;  partial = (float*)v2p;                        // alias fallback
    }

    hipMemsetAsync(v2p, 0xFF, (size_t)NGRID * 4, stream);      // v2p = -1
    hipMemsetAsync(cnt, 0, MROI * 4, stream);                  // cnt = 0
    k_scatter<<<(NVOX + 255) / 256, 256, 0, stream>>>(vcoords, v2p);
    k_build  <<<dim3(GCELLS / 256, MROI), 256, 0, stream>>>(rois, v2p, list, cnt);
    k_dots   <<<dim3(NS, MROI), 256, 0, stream>>>(vfeat, fproto, list, cnt, partial);
    k_argfin <<<MROI, 256, 0, stream>>>(partial, NS, rois, pbox, out);
}